// Round 10
// baseline (632.272 us; speedup 1.0000x reference)
//
#include <hip/hip_runtime.h>

#define DH 128
#define NB 65536   // hi16 buckets
#define CDIV(a,b) (((a)+(b)-1)/(b))

// ---------------- utility ----------------
__global__ void fill_i32(int* p, int v, int n) {
  int i = blockIdx.x * 256 + threadIdx.x;
  if (i < n) p[i] = v;
}
__global__ void fill_two_i32(int* p, int* q, int n) {
  int i = blockIdx.x * 256 + threadIdx.x;
  if (i < n) { p[i] = 0; q[i] = 0; }
}
__global__ void set_one_i32(int* p, int v) { if (threadIdx.x == 0) p[0] = v; }
__global__ void fill_hist(int* hist, int* fill2) {
  int i = blockIdx.x * 256 + threadIdx.x;
  hist[i] = 0; fill2[i] = 0;
}
// ||attn||: OpenBLAS sdot haswell order
__global__ void norm_kernel(const float* __restrict__ a, float* __restrict__ nrm) {
  if (threadIdx.x != 0) return;
  float c[4][8];
  #pragma unroll
  for (int m = 0; m < 4; ++m)
    #pragma unroll
    for (int l = 0; l < 8; ++l) c[m][l] = 0.f;
  for (int i = 0; i < 128; i += 32) {
    #pragma unroll
    for (int m = 0; m < 4; ++m)
      #pragma unroll
      for (int l = 0; l < 8; ++l) {
        float x = a[i + m * 8 + l];
        c[m][l] = fmaf(x, x, c[m][l]);
      }
  }
  float s[8];
  #pragma unroll
  for (int l = 0; l < 8; ++l) s[l] = (c[0][l] + c[1][l]) + (c[2][l] + c[3][l]);
  float b0 = s[0] + s[4], b1 = s[1] + s[5], b2 = s[2] + s[6], b3 = s[3] + s[7];
  nrm[0] = sqrtf((b0 + b1) + (b2 + b3));
}

// ---------------- generic 3-kernel exclusive scan ----------------
__global__ __launch_bounds__(256) void scanA(const int* __restrict__ in, int* __restrict__ out,
                                             int* __restrict__ bsum, int m) {
  __shared__ int buf[256];
  int i = blockIdx.x * 256 + threadIdx.x;
  int v = (i < m) ? in[i] : 0;
  buf[threadIdx.x] = v;
  __syncthreads();
  for (int off = 1; off < 256; off <<= 1) {
    int t = (threadIdx.x >= off) ? buf[threadIdx.x - off] : 0;
    __syncthreads();
    buf[threadIdx.x] += t;
    __syncthreads();
  }
  if (i < m) out[i] = buf[threadIdx.x] - v;  // exclusive
  if (threadIdx.x == 255) bsum[blockIdx.x] = buf[255];
}
__global__ __launch_bounds__(1024) void scanB(int* __restrict__ bsum, int nblk) {
  __shared__ int buf[1024];
  int v = (threadIdx.x < nblk) ? bsum[threadIdx.x] : 0;
  buf[threadIdx.x] = v;
  __syncthreads();
  for (int off = 1; off < 1024; off <<= 1) {
    int t = (threadIdx.x >= off) ? buf[threadIdx.x - off] : 0;
    __syncthreads();
    buf[threadIdx.x] += t;
    __syncthreads();
  }
  if (threadIdx.x < nblk) bsum[threadIdx.x] = buf[threadIdx.x] - v;
}
__global__ __launch_bounds__(256) void scanC(int* __restrict__ out, const int* __restrict__ bsum, int m) {
  int i = blockIdx.x * 256 + threadIdx.x;
  if (i < m) out[i] += bsum[blockIdx.x];
}

// ---------------- CSR build (deterministic) ----------------
__global__ void count_kernel(const int* __restrict__ dst, int* __restrict__ cnt, int E) {
  int e = blockIdx.x * 256 + threadIdx.x;
  if (e < E) atomicAdd(&cnt[dst[e]], 1);
}
__global__ void scatter_kernel(const int* __restrict__ dst, const int* __restrict__ rowptr,
                               int* __restrict__ fill, int* __restrict__ eids, int E) {
  int e = blockIdx.x * 256 + threadIdx.x;
  if (e >= E) return;
  int d = dst[e];
  int slot = rowptr[d] + atomicAdd(&fill[d], 1);
  eids[slot] = e;
}
__global__ void bucket_sort_kernel(const int* __restrict__ rowptr, int* __restrict__ eids, int n) {
  int v = blockIdx.x * 256 + threadIdx.x;
  if (v >= n) return;
  int lo = rowptr[v], hi = rowptr[v + 1];
  for (int a = lo + 1; a < hi; ++a) {
    int key = eids[a];
    int b = a - 1;
    while (b >= lo && eids[b] > key) { eids[b + 1] = eids[b]; --b; }
    eids[b + 1] = key;
  }
}
__global__ void count2_kernel(const int* __restrict__ src, const int* __restrict__ dst,
                              const int* __restrict__ rank, int kk, int* __restrict__ cnt2, int E) {
  int e = blockIdx.x * 256 + threadIdx.x;
  if (e >= E) return;
  int rs = rank[src[e]], rd = rank[dst[e]];
  if (rs < kk && rd < kk) atomicAdd(&cnt2[rd], 1);
}
__global__ void dinv_kernel(const int* __restrict__ cnt, float* __restrict__ dinv, int n) {
  int i = blockIdx.x * 256 + threadIdx.x;
  if (i < n) dinv[i] = 1.0f / sqrtf((float)(cnt[i] + 1));
}

// per-CSR-slot operand precompute: kills the pointer chase inside conv.
__global__ void csr_prep(const int* __restrict__ eids, const int* __restrict__ src,
                         const int* __restrict__ rank, int kk,
                         const float* __restrict__ dinv,
                         int* __restrict__ ss, float* __restrict__ ws, int E) {
  int idx = blockIdx.x * 256 + threadIdx.x;
  if (idx >= E) return;
  int s = src[eids[idx]];
  if (rank) {
    int r = rank[s];
    bool live = r < kk;
    ss[idx] = live ? r : -1;
    ws[idx] = live ? dinv[r] : 0.f;
  } else {
    ss[idx] = s;
    ws[idx] = dinv[s];
  }
}

// ---------------- GEMM (OpenBLAS rounding: per-(i,j) acc, k ascending, FMA) ----
__global__ __launch_bounds__(256) void gemm_128(const float* __restrict__ X,
                                                const float* __restrict__ W,
                                                float* __restrict__ C, int n) {
  __shared__ float Wl[128 * 128];
  for (int i = threadIdx.x * 4; i < 128 * 128; i += 1024)
    *(float4*)&Wl[i] = *(const float4*)&W[i];
  __syncthreads();

  const int row0 = blockIdx.x * 64;
  const int c0 = (threadIdx.x & 15) << 3;
  const int r0 = (threadIdx.x >> 4) << 2;

  int gr[4];
  bool inb[4];
  #pragma unroll
  for (int i = 0; i < 4; ++i) { gr[i] = row0 + r0 + i; inb[i] = gr[i] < n; }

  float acc[4][8];
  #pragma unroll
  for (int i = 0; i < 4; ++i)
    #pragma unroll
    for (int j = 0; j < 8; ++j) acc[i][j] = 0.f;

  for (int kc = 0; kc < 32; ++kc) {
    float xv[4][4];
    #pragma unroll
    for (int i = 0; i < 4; ++i) {
      float4 t = inb[i] ? *(const float4*)&X[(size_t)gr[i] * DH + kc * 4]
                        : make_float4(0.f, 0.f, 0.f, 0.f);
      xv[i][0] = t.x; xv[i][1] = t.y; xv[i][2] = t.z; xv[i][3] = t.w;
    }
    #pragma unroll
    for (int kk = 0; kk < 4; ++kk) {
      const float* wrow = &Wl[(kc * 4 + kk) * 128 + c0];
      float4 wa = *(const float4*)(wrow);
      float4 wb = *(const float4*)(wrow + 4);
      float wv[8] = {wa.x, wa.y, wa.z, wa.w, wb.x, wb.y, wb.z, wb.w};
      #pragma unroll
      for (int i = 0; i < 4; ++i)
        #pragma unroll
        for (int j = 0; j < 8; ++j)
          acc[i][j] = fmaf(xv[i][kk], wv[j], acc[i][j]);
    }
  }
  #pragma unroll
  for (int i = 0; i < 4; ++i) {
    if (inb[i]) {
      *(float4*)&C[(size_t)gr[i] * DH + c0] =
          make_float4(acc[i][0], acc[i][1], acc[i][2], acc[i][3]);
      *(float4*)&C[(size_t)gr[i] * DH + c0 + 4] =
          make_float4(acc[i][4], acc[i][5], acc[i][6], acc[i][7]);
    }
  }
}

// ---------------- GCN conv: np.add.at order, 16-wide load batching ----------------
// Chain identical to the scalar loop (ascending edge id, mul then add, dead edges
// branch-skipped); only LOADS are batched (deg<=16 in one latency round, 97% of nodes).
__global__ __launch_bounds__(256) void conv_kernel(
    const float* __restrict__ h, const float* __restrict__ bias,
    const int* __restrict__ rowptr,
    const int* __restrict__ ss, const float* __restrict__ ws,
    const int* __restrict__ sel,   // level2: new->orig (null for level1)
    const float* __restrict__ dinv,
    float* __restrict__ out, int nodes) {
  #pragma clang fp contract(off)
  int node = blockIdx.x * 2 + (threadIdx.x >> 7);
  int dim = threadIdx.x & 127;
  if (node >= nodes) return;
  int v_orig = sel ? sel[node] : node;
  float dv = dinv[node];
  float acc = 0.f;
  int lo = rowptr[v_orig], hi = rowptr[v_orig + 1];
  for (int base = lo; base < hi; base += 16) {
    int cnt = hi - base; if (cnt > 16) cnt = 16;
    int   sq[16];
    float nm[16];
    float hv[16];
    #pragma unroll
    for (int q = 0; q < 16; ++q) {
      if (q < cnt) {
        int sh = ss[base + q];
        sq[q] = sh;
        nm[q] = ws[base + q] * dv;
        hv[q] = (sh >= 0) ? h[(size_t)sh * DH + dim] : 0.f;
      }
    }
    #pragma unroll
    for (int q = 0; q < 16; ++q) {
      if (q < cnt && sq[q] >= 0) {
        float t = hv[q] * nm[q];
        acc = acc + t;
      }
    }
  }
  float selft = h[(size_t)node * DH + dim] * (dv * dv);
  float r = (acc + selft) + bias[dim];
  out[(size_t)node * DH + dim] = r > 0.f ? r : 0.f;
}

// ---------------- score: OpenBLAS sgemv_t haswell rounding ----------------
__global__ __launch_bounds__(256) void score_kernel(const float* __restrict__ h,
    const float* __restrict__ attn, const float* __restrict__ nrm,
    float* __restrict__ score, int n) {
  __shared__ float at[128];
  if (threadIdx.x < 32) {
    *(float4*)&at[threadIdx.x * 4] = *(const float4*)&attn[threadIdx.x * 4];
  }
  __syncthreads();
  int row = blockIdx.x * 256 + threadIdx.x;
  if (row >= n) return;
  const float* hr = &h[(size_t)row * DH];
  float c[16];
  #pragma unroll
  for (int j = 0; j < 16; ++j) c[j] = 0.f;
  #pragma unroll
  for (int t = 0; t < 8; ++t) {
    #pragma unroll
    for (int j4 = 0; j4 < 4; ++j4) {
      float4 hv = *(const float4*)&hr[t * 16 + j4 * 4];
      float4 av = *(const float4*)&at[t * 16 + j4 * 4];
      c[j4 * 4 + 0] = fmaf(hv.x, av.x, c[j4 * 4 + 0]);
      c[j4 * 4 + 1] = fmaf(hv.y, av.y, c[j4 * 4 + 1]);
      c[j4 * 4 + 2] = fmaf(hv.z, av.z, c[j4 * 4 + 2]);
      c[j4 * 4 + 3] = fmaf(hv.w, av.w, c[j4 * 4 + 3]);
    }
  }
  float s8[8];
  #pragma unroll
  for (int l = 0; l < 8; ++l) s8[l] = c[l] + c[l + 8];
  float s4[4];
  #pragma unroll
  for (int l = 0; l < 4; ++l) s4[l] = s8[l] + s8[l + 4];
  float dot = (s4[0] + s4[1]) + (s4[2] + s4[3]);
  float q = dot / nrm[0];
  score[row] = (float)tanh((double)q);
}

// ---------------- bucketed exact ranking ----------------
// fused keys + histogram
__global__ void keys_hist_kernel(const float* __restrict__ score, unsigned* __restrict__ s32,
                                 int* __restrict__ hist, int n) {
  int i = blockIdx.x * 256 + threadIdx.x;
  if (i >= n) return;
  unsigned u = __float_as_uint(score[i]);
  unsigned s = (u & 0x80000000u) ? ~u : (u | 0x80000000u);
  s32[i] = s;
  atomicAdd(&hist[s >> 16], 1);
}
__global__ void scatter32_kernel(const unsigned* __restrict__ s32, const int* __restrict__ start,
                                 int* __restrict__ fill2, unsigned long long* __restrict__ mem64,
                                 int n) {
  int i = blockIdx.x * 256 + threadIdx.x;
  if (i >= n) return;
  unsigned si = s32[i];
  int b = si >> 16;
  int pos = start[b] + atomicAdd(&fill2[b], 1);
  mem64[pos] = ((unsigned long long)si << 32) | (unsigned)(~i);
}
__global__ void rank_bucket_kernel(const unsigned* __restrict__ s32, const int* __restrict__ start,
                                   const int* __restrict__ hist,
                                   const unsigned long long* __restrict__ mem64,
                                   int n, int* __restrict__ rank) {
  int i = blockIdx.x * 256 + threadIdx.x;
  if (i >= n) return;
  unsigned si = s32[i];
  int b = si >> 16;
  int lo = start[b], m = hist[b];
  unsigned long long ki = ((unsigned long long)si << 32) | (unsigned)(~i);
  int cnt = n - lo - m;  // all elements in higher buckets have greater keys
  for (int t = 0; t < m; ++t) cnt += (mem64[lo + t] > ki) ? 1 : 0;
  rank[i] = cnt;
}

__global__ void select_kernel(const float* __restrict__ score, const int* __restrict__ rank,
                              int k, int* __restrict__ sel, float* __restrict__ vals, int n) {
  int i = blockIdx.x * 256 + threadIdx.x;
  if (i >= n) return;
  int r = rank[i];
  if (r < k) { sel[r] = i; vals[r] = score[i]; }
}

__global__ __launch_bounds__(256) void gather_kernel(const float* __restrict__ h,
    const int* __restrict__ sel, const float* __restrict__ vals,
    float* __restrict__ out, int k) {
  int lane = threadIdx.x & 31;
  int r = blockIdx.x * 8 + (threadIdx.x >> 5);
  if (r >= k) return;
  float v = vals[r];
  int s = sel[r];
  float4 x = *(const float4*)&h[(size_t)s * DH + (lane << 2)];
  *(float4*)&out[(size_t)r * DH + (lane << 2)] =
      make_float4(x.x * v, x.y * v, x.z * v, x.w * v);
}

// ---------------- host ----------------
extern "C" void kernel_launch(void* const* d_in, const int* in_sizes, int n_in,
                              void* d_out, int out_size, void* d_ws, size_t ws_size,
                              hipStream_t stream) {
  const float* X  = (const float*)d_in[0];
  const int*   ei = (const int*)d_in[1];
  const float* W1 = (const float*)d_in[3];
  const float* b1 = (const float*)d_in[4];
  const float* a1 = (const float*)d_in[5];
  const float* W2 = (const float*)d_in[6];
  const float* b2 = (const float*)d_in[7];
  const float* a2 = (const float*)d_in[8];
  float* out = (float*)d_out;

  const int n  = in_sizes[0] / DH;
  const int E  = in_sizes[1] / 2;
  const int k1 = (4 * n + 4) / 5;
  const int k2 = (4 * k1 + 4) / 5;
  const int* src = ei;
  const int* dst = ei + E;

  char* w = (char*)d_ws;
  size_t off = 0;
  auto alloc = [&](size_t bytes) { void* p = w + off; off += (bytes + 255) & ~(size_t)255; return p; };
  float* hA     = (float*)alloc((size_t)n * DH * 4);
  float* hB     = (float*)alloc((size_t)n * DH * 4);
  float* xp     = (float*)alloc((size_t)k1 * DH * 4);
  int*   cnt    = (int*)  alloc((size_t)n * 4);
  int*   rowptr = (int*)  alloc((size_t)(n + 1) * 4);
  int*   fill   = (int*)  alloc((size_t)n * 4);
  int*   eids   = (int*)  alloc((size_t)E * 4);
  int*   ss     = (int*)  alloc((size_t)E * 4);
  float* ws     = (float*)alloc((size_t)E * 4);
  int*   cnt2   = (int*)  alloc((size_t)k1 * 4);
  float* dinv1  = (float*)alloc((size_t)n * 4);
  float* dinv2  = (float*)alloc((size_t)k1 * 4);
  float* score1 = (float*)alloc((size_t)n * 4);
  float* score2 = (float*)alloc((size_t)k1 * 4);
  int*   rank1  = (int*)  alloc((size_t)n * 4);
  int*   rank2  = (int*)  alloc((size_t)k1 * 4);
  unsigned* s32 = (unsigned*)alloc((size_t)n * 4);
  int*   hist   = (int*)  alloc((size_t)NB * 4);
  int*   start  = (int*)  alloc((size_t)NB * 4);
  int*   fill2  = (int*)  alloc((size_t)NB * 4);
  unsigned long long* mem64 = (unsigned long long*)alloc((size_t)n * 8);
  int*   bsum   = (int*)  alloc((size_t)1024 * 4);
  int*   sel1   = (int*)  alloc((size_t)k1 * 4);
  float* vals1  = (float*)alloc((size_t)k1 * 4);
  int*   sel2   = (int*)  alloc((size_t)k2 * 4);
  float* vals2  = (float*)alloc((size_t)k2 * 4);
  float* nrm1   = (float*)alloc(256);
  float* nrm2   = (float*)alloc(256);

  auto scan3 = [&](const int* in, int* outp, int m) {
    int nblk = CDIV(m, 256);
    scanA<<<nblk, 256, 0, stream>>>(in, outp, bsum, m);
    scanB<<<1, 1024, 0, stream>>>(bsum, nblk);
    scanC<<<nblk, 256, 0, stream>>>(outp, bsum, m);
  };
  auto rank_pass = [&](const float* score, int* rank, int nL) {
    fill_hist<<<NB / 256, 256, 0, stream>>>(hist, fill2);
    keys_hist_kernel<<<CDIV(nL, 256), 256, 0, stream>>>(score, s32, hist, nL);
    scan3(hist, start, NB);
    scatter32_kernel<<<CDIV(nL, 256), 256, 0, stream>>>(s32, start, fill2, mem64, nL);
    rank_bucket_kernel<<<CDIV(nL, 256), 256, 0, stream>>>(s32, start, hist, mem64, nL, rank);
  };

  // ---- CSR build ----
  fill_two_i32<<<CDIV(n, 256), 256, 0, stream>>>(cnt, fill, n);
  count_kernel<<<CDIV(E, 256), 256, 0, stream>>>(dst, cnt, E);
  scan3(cnt, rowptr, n);
  set_one_i32<<<1, 64, 0, stream>>>(rowptr + n, E);
  scatter_kernel<<<CDIV(E, 256), 256, 0, stream>>>(dst, rowptr, fill, eids, E);
  bucket_sort_kernel<<<CDIV(n, 256), 256, 0, stream>>>(rowptr, eids, n);

  // ---- level 1 ----
  norm_kernel<<<1, 64, 0, stream>>>(a1, nrm1);
  gemm_128<<<CDIV(n, 64), 256, 0, stream>>>(X, W1, hA, n);
  dinv_kernel<<<CDIV(n, 256), 256, 0, stream>>>(cnt, dinv1, n);
  csr_prep<<<CDIV(E, 256), 256, 0, stream>>>(eids, src, nullptr, 0, dinv1, ss, ws, E);
  conv_kernel<<<CDIV(n, 2), 256, 0, stream>>>(hA, b1, rowptr, ss, ws,
                                              nullptr, dinv1, hB, n);
  score_kernel<<<CDIV(n, 256), 256, 0, stream>>>(hB, a1, nrm1, score1, n);
  rank_pass(score1, rank1, n);
  select_kernel<<<CDIV(n, 256), 256, 0, stream>>>(score1, rank1, k1, sel1, vals1, n);
  gather_kernel<<<CDIV(k1, 8), 256, 0, stream>>>(hB, sel1, vals1, xp, k1);

  // ---- level 2 ----
  norm_kernel<<<1, 64, 0, stream>>>(a2, nrm2);
  gemm_128<<<CDIV(k1, 64), 256, 0, stream>>>(xp, W2, hA, k1);
  fill_i32<<<CDIV(k1, 256), 256, 0, stream>>>(cnt2, 0, k1);
  count2_kernel<<<CDIV(E, 256), 256, 0, stream>>>(src, dst, rank1, k1, cnt2, E);
  dinv_kernel<<<CDIV(k1, 256), 256, 0, stream>>>(cnt2, dinv2, k1);
  csr_prep<<<CDIV(E, 256), 256, 0, stream>>>(eids, src, rank1, k1, dinv2, ss, ws, E);
  conv_kernel<<<CDIV(k1, 2), 256, 0, stream>>>(hA, b2, rowptr, ss, ws,
                                               sel1, dinv2, hB, k1);
  score_kernel<<<CDIV(k1, 256), 256, 0, stream>>>(hB, a2, nrm2, score2, k1);
  rank_pass(score2, rank2, k1);
  select_kernel<<<CDIV(k1, 256), 256, 0, stream>>>(score2, rank2, k2, sel2, vals2, k1);
  gather_kernel<<<CDIV(k2, 8), 256, 0, stream>>>(hB, sel2, vals2, out, k2);
}

// Round 11
// 584.177 us; speedup vs baseline: 1.0823x; 1.0823x over previous
//
#include <hip/hip_runtime.h>

#define DH 128
#define NB 65536   // hi16 buckets
#define CDIV(a,b) (((a)+(b)-1)/(b))

// ---------------- utility ----------------
__global__ void fill_i32(int* p, int v, int n) {
  int i = blockIdx.x * 256 + threadIdx.x;
  if (i < n) p[i] = v;
}
__global__ void fill_two_i32(int* p, int* q, int n) {
  int i = blockIdx.x * 256 + threadIdx.x;
  if (i < n) { p[i] = 0; q[i] = 0; }
}
__global__ void set_one_i32(int* p, int v) { if (threadIdx.x == 0) p[0] = v; }
__global__ void fill_hist(int* hist, int* fill2) {
  int i = blockIdx.x * 256 + threadIdx.x;
  hist[i] = 0; fill2[i] = 0;
}
// ||attn||: OpenBLAS sdot haswell order
__global__ void norm_kernel(const float* __restrict__ a, float* __restrict__ nrm) {
  if (threadIdx.x != 0) return;
  float c[4][8];
  #pragma unroll
  for (int m = 0; m < 4; ++m)
    #pragma unroll
    for (int l = 0; l < 8; ++l) c[m][l] = 0.f;
  for (int i = 0; i < 128; i += 32) {
    #pragma unroll
    for (int m = 0; m < 4; ++m)
      #pragma unroll
      for (int l = 0; l < 8; ++l) {
        float x = a[i + m * 8 + l];
        c[m][l] = fmaf(x, x, c[m][l]);
      }
  }
  float s[8];
  #pragma unroll
  for (int l = 0; l < 8; ++l) s[l] = (c[0][l] + c[1][l]) + (c[2][l] + c[3][l]);
  float b0 = s[0] + s[4], b1 = s[1] + s[5], b2 = s[2] + s[6], b3 = s[3] + s[7];
  nrm[0] = sqrtf((b0 + b1) + (b2 + b3));
}

// ---------------- generic 3-kernel exclusive scan ----------------
__global__ __launch_bounds__(256) void scanA(const int* __restrict__ in, int* __restrict__ out,
                                             int* __restrict__ bsum, int m) {
  __shared__ int buf[256];
  int i = blockIdx.x * 256 + threadIdx.x;
  int v = (i < m) ? in[i] : 0;
  buf[threadIdx.x] = v;
  __syncthreads();
  for (int off = 1; off < 256; off <<= 1) {
    int t = (threadIdx.x >= off) ? buf[threadIdx.x - off] : 0;
    __syncthreads();
    buf[threadIdx.x] += t;
    __syncthreads();
  }
  if (i < m) out[i] = buf[threadIdx.x] - v;  // exclusive
  if (threadIdx.x == 255) bsum[blockIdx.x] = buf[255];
}
__global__ __launch_bounds__(1024) void scanB(int* __restrict__ bsum, int nblk) {
  __shared__ int buf[1024];
  int v = (threadIdx.x < nblk) ? bsum[threadIdx.x] : 0;
  buf[threadIdx.x] = v;
  __syncthreads();
  for (int off = 1; off < 1024; off <<= 1) {
    int t = (threadIdx.x >= off) ? buf[threadIdx.x - off] : 0;
    __syncthreads();
    buf[threadIdx.x] += t;
    __syncthreads();
  }
  if (threadIdx.x < nblk) bsum[threadIdx.x] = buf[threadIdx.x] - v;
}
__global__ __launch_bounds__(256) void scanC(int* __restrict__ out, const int* __restrict__ bsum, int m) {
  int i = blockIdx.x * 256 + threadIdx.x;
  if (i < m) out[i] += bsum[blockIdx.x];
}

// ---------------- CSR build (deterministic) ----------------
__global__ void count_kernel(const int* __restrict__ dst, int* __restrict__ cnt, int E) {
  int e = blockIdx.x * 256 + threadIdx.x;
  if (e < E) atomicAdd(&cnt[dst[e]], 1);
}
__global__ void scatter_kernel(const int* __restrict__ dst, const int* __restrict__ rowptr,
                               int* __restrict__ fill, int* __restrict__ eids, int E) {
  int e = blockIdx.x * 256 + threadIdx.x;
  if (e >= E) return;
  int d = dst[e];
  int slot = rowptr[d] + atomicAdd(&fill[d], 1);
  eids[slot] = e;
}
__global__ void bucket_sort_kernel(const int* __restrict__ rowptr, int* __restrict__ eids, int n) {
  int v = blockIdx.x * 256 + threadIdx.x;
  if (v >= n) return;
  int lo = rowptr[v], hi = rowptr[v + 1];
  for (int a = lo + 1; a < hi; ++a) {
    int key = eids[a];
    int b = a - 1;
    while (b >= lo && eids[b] > key) { eids[b + 1] = eids[b]; --b; }
    eids[b + 1] = key;
  }
}
__global__ void count2_kernel(const int* __restrict__ src, const int* __restrict__ dst,
                              const int* __restrict__ rank, int kk, int* __restrict__ cnt2, int E) {
  int e = blockIdx.x * 256 + threadIdx.x;
  if (e >= E) return;
  int rs = rank[src[e]], rd = rank[dst[e]];
  if (rs < kk && rd < kk) atomicAdd(&cnt2[rd], 1);
}
__global__ void dinv_kernel(const int* __restrict__ cnt, float* __restrict__ dinv, int n) {
  int i = blockIdx.x * 256 + threadIdx.x;
  if (i < n) dinv[i] = 1.0f / sqrtf((float)(cnt[i] + 1));
}

// per-CSR-slot operand precompute: kills the pointer chase inside conv.
__global__ void csr_prep(const int* __restrict__ eids, const int* __restrict__ src,
                         const int* __restrict__ rank, int kk,
                         const float* __restrict__ dinv,
                         int* __restrict__ ss, float* __restrict__ ws, int E) {
  int idx = blockIdx.x * 256 + threadIdx.x;
  if (idx >= E) return;
  int s = src[eids[idx]];
  if (rank) {
    int r = rank[s];
    bool live = r < kk;
    ss[idx] = live ? r : -1;
    ws[idx] = live ? dinv[r] : 0.f;
  } else {
    ss[idx] = s;
    ws[idx] = dinv[s];
  }
}

// ---------------- GEMM (OpenBLAS rounding: per-(i,j) acc, k ascending, FMA) ----
// W read directly from global (64 KiB, shared by all blocks -> L2 broadcast).
// No LDS => no 2-blocks/CU occupancy cap, no staging serialization.
__global__ __launch_bounds__(256) void gemm_128(const float* __restrict__ X,
                                                const float* __restrict__ W,
                                                float* __restrict__ C, int n) {
  const int row0 = blockIdx.x * 64;
  const int c0 = (threadIdx.x & 15) << 3;
  const int r0 = (threadIdx.x >> 4) << 2;

  int gr[4];
  bool inb[4];
  #pragma unroll
  for (int i = 0; i < 4; ++i) { gr[i] = row0 + r0 + i; inb[i] = gr[i] < n; }

  float acc[4][8];
  #pragma unroll
  for (int i = 0; i < 4; ++i)
    #pragma unroll
    for (int j = 0; j < 8; ++j) acc[i][j] = 0.f;

  for (int kc = 0; kc < 32; ++kc) {
    float xv[4][4];
    #pragma unroll
    for (int i = 0; i < 4; ++i) {
      float4 t = inb[i] ? *(const float4*)&X[(size_t)gr[i] * DH + kc * 4]
                        : make_float4(0.f, 0.f, 0.f, 0.f);
      xv[i][0] = t.x; xv[i][1] = t.y; xv[i][2] = t.z; xv[i][3] = t.w;
    }
    #pragma unroll
    for (int kk = 0; kk < 4; ++kk) {
      const float* wrow = &W[(kc * 4 + kk) * 128 + c0];
      float4 wa = *(const float4*)(wrow);
      float4 wb = *(const float4*)(wrow + 4);
      float wv[8] = {wa.x, wa.y, wa.z, wa.w, wb.x, wb.y, wb.z, wb.w};
      #pragma unroll
      for (int i = 0; i < 4; ++i)
        #pragma unroll
        for (int j = 0; j < 8; ++j)
          acc[i][j] = fmaf(xv[i][kk], wv[j], acc[i][j]);
    }
  }
  #pragma unroll
  for (int i = 0; i < 4; ++i) {
    if (inb[i]) {
      *(float4*)&C[(size_t)gr[i] * DH + c0] =
          make_float4(acc[i][0], acc[i][1], acc[i][2], acc[i][3]);
      *(float4*)&C[(size_t)gr[i] * DH + c0 + 4] =
          make_float4(acc[i][4], acc[i][5], acc[i][6], acc[i][7]);
    }
  }
}

// ---------------- GCN conv: np.add.at order, 8-wide load batching ----------------
// (R9 version — 16-wide regressed: VGPR 24->40 cost occupancy 71->55%, +25% time.)
__global__ __launch_bounds__(256) void conv_kernel(
    const float* __restrict__ h, const float* __restrict__ bias,
    const int* __restrict__ rowptr,
    const int* __restrict__ ss, const float* __restrict__ ws,
    const int* __restrict__ sel,   // level2: new->orig (null for level1)
    const float* __restrict__ dinv,
    float* __restrict__ out, int nodes) {
  #pragma clang fp contract(off)
  int node = blockIdx.x * 2 + (threadIdx.x >> 7);
  int dim = threadIdx.x & 127;
  if (node >= nodes) return;
  int v_orig = sel ? sel[node] : node;
  float dv = dinv[node];
  float acc = 0.f;
  int lo = rowptr[v_orig], hi = rowptr[v_orig + 1];
  for (int base = lo; base < hi; base += 8) {
    int cnt = hi - base; if (cnt > 8) cnt = 8;
    int   sq[8];
    float nm[8];
    float hv[8];
    #pragma unroll
    for (int q = 0; q < 8; ++q) {
      if (q < cnt) {
        int sh = ss[base + q];
        sq[q] = sh;
        nm[q] = ws[base + q] * dv;
        hv[q] = (sh >= 0) ? h[(size_t)sh * DH + dim] : 0.f;
      }
    }
    #pragma unroll
    for (int q = 0; q < 8; ++q) {
      if (q < cnt && sq[q] >= 0) {
        float t = hv[q] * nm[q];
        acc = acc + t;
      }
    }
  }
  float selft = h[(size_t)node * DH + dim] * (dv * dv);
  float r = (acc + selft) + bias[dim];
  out[(size_t)node * DH + dim] = r > 0.f ? r : 0.f;
}

// ---------------- score: OpenBLAS sgemv_t haswell rounding ----------------
__global__ __launch_bounds__(256) void score_kernel(const float* __restrict__ h,
    const float* __restrict__ attn, const float* __restrict__ nrm,
    float* __restrict__ score, int n) {
  __shared__ float at[128];
  if (threadIdx.x < 32) {
    *(float4*)&at[threadIdx.x * 4] = *(const float4*)&attn[threadIdx.x * 4];
  }
  __syncthreads();
  int row = blockIdx.x * 256 + threadIdx.x;
  if (row >= n) return;
  const float* hr = &h[(size_t)row * DH];
  float c[16];
  #pragma unroll
  for (int j = 0; j < 16; ++j) c[j] = 0.f;
  #pragma unroll
  for (int t = 0; t < 8; ++t) {
    #pragma unroll
    for (int j4 = 0; j4 < 4; ++j4) {
      float4 hv = *(const float4*)&hr[t * 16 + j4 * 4];
      float4 av = *(const float4*)&at[t * 16 + j4 * 4];
      c[j4 * 4 + 0] = fmaf(hv.x, av.x, c[j4 * 4 + 0]);
      c[j4 * 4 + 1] = fmaf(hv.y, av.y, c[j4 * 4 + 1]);
      c[j4 * 4 + 2] = fmaf(hv.z, av.z, c[j4 * 4 + 2]);
      c[j4 * 4 + 3] = fmaf(hv.w, av.w, c[j4 * 4 + 3]);
    }
  }
  float s8[8];
  #pragma unroll
  for (int l = 0; l < 8; ++l) s8[l] = c[l] + c[l + 8];
  float s4[4];
  #pragma unroll
  for (int l = 0; l < 4; ++l) s4[l] = s8[l] + s8[l + 4];
  float dot = (s4[0] + s4[1]) + (s4[2] + s4[3]);
  float q = dot / nrm[0];
  score[row] = (float)tanh((double)q);
}

// ---------------- bucketed exact ranking ----------------
__global__ void keys_hist_kernel(const float* __restrict__ score, unsigned* __restrict__ s32,
                                 int* __restrict__ hist, int n) {
  int i = blockIdx.x * 256 + threadIdx.x;
  if (i >= n) return;
  unsigned u = __float_as_uint(score[i]);
  unsigned s = (u & 0x80000000u) ? ~u : (u | 0x80000000u);
  s32[i] = s;
  atomicAdd(&hist[s >> 16], 1);
}
__global__ void scatter32_kernel(const unsigned* __restrict__ s32, const int* __restrict__ start,
                                 int* __restrict__ fill2, unsigned long long* __restrict__ mem64,
                                 int n) {
  int i = blockIdx.x * 256 + threadIdx.x;
  if (i >= n) return;
  unsigned si = s32[i];
  int b = si >> 16;
  int pos = start[b] + atomicAdd(&fill2[b], 1);
  mem64[pos] = ((unsigned long long)si << 32) | (unsigned)(~i);
}
__global__ void rank_bucket_kernel(const unsigned* __restrict__ s32, const int* __restrict__ start,
                                   const int* __restrict__ hist,
                                   const unsigned long long* __restrict__ mem64,
                                   int n, int* __restrict__ rank) {
  int i = blockIdx.x * 256 + threadIdx.x;
  if (i >= n) return;
  unsigned si = s32[i];
  int b = si >> 16;
  int lo = start[b], m = hist[b];
  unsigned long long ki = ((unsigned long long)si << 32) | (unsigned)(~i);
  int cnt = n - lo - m;  // all elements in higher buckets have greater keys
  for (int t = 0; t < m; ++t) cnt += (mem64[lo + t] > ki) ? 1 : 0;
  rank[i] = cnt;
}

__global__ void select_kernel(const float* __restrict__ score, const int* __restrict__ rank,
                              int k, int* __restrict__ sel, float* __restrict__ vals, int n) {
  int i = blockIdx.x * 256 + threadIdx.x;
  if (i >= n) return;
  int r = rank[i];
  if (r < k) { sel[r] = i; vals[r] = score[i]; }
}

__global__ __launch_bounds__(256) void gather_kernel(const float* __restrict__ h,
    const int* __restrict__ sel, const float* __restrict__ vals,
    float* __restrict__ out, int k) {
  int lane = threadIdx.x & 31;
  int r = blockIdx.x * 8 + (threadIdx.x >> 5);
  if (r >= k) return;
  float v = vals[r];
  int s = sel[r];
  float4 x = *(const float4*)&h[(size_t)s * DH + (lane << 2)];
  *(float4*)&out[(size_t)r * DH + (lane << 2)] =
      make_float4(x.x * v, x.y * v, x.z * v, x.w * v);
}

// ---------------- host ----------------
extern "C" void kernel_launch(void* const* d_in, const int* in_sizes, int n_in,
                              void* d_out, int out_size, void* d_ws, size_t ws_size,
                              hipStream_t stream) {
  const float* X  = (const float*)d_in[0];
  const int*   ei = (const int*)d_in[1];
  const float* W1 = (const float*)d_in[3];
  const float* b1 = (const float*)d_in[4];
  const float* a1 = (const float*)d_in[5];
  const float* W2 = (const float*)d_in[6];
  const float* b2 = (const float*)d_in[7];
  const float* a2 = (const float*)d_in[8];
  float* out = (float*)d_out;

  const int n  = in_sizes[0] / DH;
  const int E  = in_sizes[1] / 2;
  const int k1 = (4 * n + 4) / 5;
  const int k2 = (4 * k1 + 4) / 5;
  const int* src = ei;
  const int* dst = ei + E;

  char* w = (char*)d_ws;
  size_t off = 0;
  auto alloc = [&](size_t bytes) { void* p = w + off; off += (bytes + 255) & ~(size_t)255; return p; };
  float* hA     = (float*)alloc((size_t)n * DH * 4);
  float* hB     = (float*)alloc((size_t)n * DH * 4);
  float* xp     = (float*)alloc((size_t)k1 * DH * 4);
  int*   cnt    = (int*)  alloc((size_t)n * 4);
  int*   rowptr = (int*)  alloc((size_t)(n + 1) * 4);
  int*   fill   = (int*)  alloc((size_t)n * 4);
  int*   eids   = (int*)  alloc((size_t)E * 4);
  int*   ss     = (int*)  alloc((size_t)E * 4);
  float* ws     = (float*)alloc((size_t)E * 4);
  int*   cnt2   = (int*)  alloc((size_t)k1 * 4);
  float* dinv1  = (float*)alloc((size_t)n * 4);
  float* dinv2  = (float*)alloc((size_t)k1 * 4);
  float* score1 = (float*)alloc((size_t)n * 4);
  float* score2 = (float*)alloc((size_t)k1 * 4);
  int*   rank1  = (int*)  alloc((size_t)n * 4);
  int*   rank2  = (int*)  alloc((size_t)k1 * 4);
  unsigned* s32 = (unsigned*)alloc((size_t)n * 4);
  int*   hist   = (int*)  alloc((size_t)NB * 4);
  int*   start  = (int*)  alloc((size_t)NB * 4);
  int*   fill2  = (int*)  alloc((size_t)NB * 4);
  unsigned long long* mem64 = (unsigned long long*)alloc((size_t)n * 8);
  int*   bsum   = (int*)  alloc((size_t)1024 * 4);
  int*   sel1   = (int*)  alloc((size_t)k1 * 4);
  float* vals1  = (float*)alloc((size_t)k1 * 4);
  int*   sel2   = (int*)  alloc((size_t)k2 * 4);
  float* vals2  = (float*)alloc((size_t)k2 * 4);
  float* nrm1   = (float*)alloc(256);
  float* nrm2   = (float*)alloc(256);

  auto scan3 = [&](const int* in, int* outp, int m) {
    int nblk = CDIV(m, 256);
    scanA<<<nblk, 256, 0, stream>>>(in, outp, bsum, m);
    scanB<<<1, 1024, 0, stream>>>(bsum, nblk);
    scanC<<<nblk, 256, 0, stream>>>(outp, bsum, m);
  };
  auto rank_pass = [&](const float* score, int* rank, int nL) {
    fill_hist<<<NB / 256, 256, 0, stream>>>(hist, fill2);
    keys_hist_kernel<<<CDIV(nL, 256), 256, 0, stream>>>(score, s32, hist, nL);
    scan3(hist, start, NB);
    scatter32_kernel<<<CDIV(nL, 256), 256, 0, stream>>>(s32, start, fill2, mem64, nL);
    rank_bucket_kernel<<<CDIV(nL, 256), 256, 0, stream>>>(s32, start, hist, mem64, nL, rank);
  };

  // ---- CSR build ----
  fill_two_i32<<<CDIV(n, 256), 256, 0, stream>>>(cnt, fill, n);
  count_kernel<<<CDIV(E, 256), 256, 0, stream>>>(dst, cnt, E);
  scan3(cnt, rowptr, n);
  set_one_i32<<<1, 64, 0, stream>>>(rowptr + n, E);
  scatter_kernel<<<CDIV(E, 256), 256, 0, stream>>>(dst, rowptr, fill, eids, E);
  bucket_sort_kernel<<<CDIV(n, 256), 256, 0, stream>>>(rowptr, eids, n);

  // ---- level 1 ----
  norm_kernel<<<1, 64, 0, stream>>>(a1, nrm1);
  gemm_128<<<CDIV(n, 64), 256, 0, stream>>>(X, W1, hA, n);
  dinv_kernel<<<CDIV(n, 256), 256, 0, stream>>>(cnt, dinv1, n);
  csr_prep<<<CDIV(E, 256), 256, 0, stream>>>(eids, src, nullptr, 0, dinv1, ss, ws, E);
  conv_kernel<<<CDIV(n, 2), 256, 0, stream>>>(hA, b1, rowptr, ss, ws,
                                              nullptr, dinv1, hB, n);
  score_kernel<<<CDIV(n, 256), 256, 0, stream>>>(hB, a1, nrm1, score1, n);
  rank_pass(score1, rank1, n);
  select_kernel<<<CDIV(n, 256), 256, 0, stream>>>(score1, rank1, k1, sel1, vals1, n);
  gather_kernel<<<CDIV(k1, 8), 256, 0, stream>>>(hB, sel1, vals1, xp, k1);

  // ---- level 2 ----
  norm_kernel<<<1, 64, 0, stream>>>(a2, nrm2);
  gemm_128<<<CDIV(k1, 64), 256, 0, stream>>>(xp, W2, hA, k1);
  fill_i32<<<CDIV(k1, 256), 256, 0, stream>>>(cnt2, 0, k1);
  count2_kernel<<<CDIV(E, 256), 256, 0, stream>>>(src, dst, rank1, k1, cnt2, E);
  dinv_kernel<<<CDIV(k1, 256), 256, 0, stream>>>(cnt2, dinv2, k1);
  csr_prep<<<CDIV(E, 256), 256, 0, stream>>>(eids, src, rank1, k1, dinv2, ss, ws, E);
  conv_kernel<<<CDIV(k1, 2), 256, 0, stream>>>(hA, b2, rowptr, ss, ws,
                                               sel1, dinv2, hB, k1);
  score_kernel<<<CDIV(k1, 256), 256, 0, stream>>>(hB, a2, nrm2, score2, k1);
  rank_pass(score2, rank2, k1);
  select_kernel<<<CDIV(k1, 256), 256, 0, stream>>>(score2, rank2, k2, sel2, vals2, k1);
  gather_kernel<<<CDIV(k2, 8), 256, 0, stream>>>(hB, sel2, vals2, out, k2);
}

// Round 12
// 499.925 us; speedup vs baseline: 1.2647x; 1.1685x over previous
//
#include <hip/hip_runtime.h>

#define DH 128
#define NB 65536   // hi16 buckets
#define CDIV(a,b) (((a)+(b)-1)/(b))

// ---------------- utility ----------------
__global__ void fill_i32(int* p, int v, int n) {
  int i = blockIdx.x * 256 + threadIdx.x;
  if (i < n) p[i] = v;
}
__global__ void fill_two_i32(int* p, int* q, int n) {
  int i = blockIdx.x * 256 + threadIdx.x;
  if (i < n) { p[i] = 0; q[i] = 0; }
}
__global__ void set_one_i32(int* p, int v) { if (threadIdx.x == 0) p[0] = v; }
__global__ void fill_hist(int* hist, int* fill2) {
  int i = blockIdx.x * 256 + threadIdx.x;
  hist[i] = 0; fill2[i] = 0;
}
__global__ void fill_pk(int2* pk, int P) {
  int i = blockIdx.x * 256 + threadIdx.x;
  if (i < P) pk[i] = make_int2(0, 0);
}
// ||attn||: OpenBLAS sdot haswell order
__global__ void norm_kernel(const float* __restrict__ a, float* __restrict__ nrm) {
  if (threadIdx.x != 0) return;
  float c[4][8];
  #pragma unroll
  for (int m = 0; m < 4; ++m)
    #pragma unroll
    for (int l = 0; l < 8; ++l) c[m][l] = 0.f;
  for (int i = 0; i < 128; i += 32) {
    #pragma unroll
    for (int m = 0; m < 4; ++m)
      #pragma unroll
      for (int l = 0; l < 8; ++l) {
        float x = a[i + m * 8 + l];
        c[m][l] = fmaf(x, x, c[m][l]);
      }
  }
  float s[8];
  #pragma unroll
  for (int l = 0; l < 8; ++l) s[l] = (c[0][l] + c[1][l]) + (c[2][l] + c[3][l]);
  float b0 = s[0] + s[4], b1 = s[1] + s[5], b2 = s[2] + s[6], b3 = s[3] + s[7];
  nrm[0] = sqrtf((b0 + b1) + (b2 + b3));
}

// ---------------- generic 3-kernel exclusive scan ----------------
__global__ __launch_bounds__(256) void scanA(const int* __restrict__ in, int* __restrict__ out,
                                             int* __restrict__ bsum, int m) {
  __shared__ int buf[256];
  int i = blockIdx.x * 256 + threadIdx.x;
  int v = (i < m) ? in[i] : 0;
  buf[threadIdx.x] = v;
  __syncthreads();
  for (int off = 1; off < 256; off <<= 1) {
    int t = (threadIdx.x >= off) ? buf[threadIdx.x - off] : 0;
    __syncthreads();
    buf[threadIdx.x] += t;
    __syncthreads();
  }
  if (i < m) out[i] = buf[threadIdx.x] - v;  // exclusive
  if (threadIdx.x == 255) bsum[blockIdx.x] = buf[255];
}
__global__ __launch_bounds__(1024) void scanB(int* __restrict__ bsum, int nblk) {
  __shared__ int buf[1024];
  int v = (threadIdx.x < nblk) ? bsum[threadIdx.x] : 0;
  buf[threadIdx.x] = v;
  __syncthreads();
  for (int off = 1; off < 1024; off <<= 1) {
    int t = (threadIdx.x >= off) ? buf[threadIdx.x - off] : 0;
    __syncthreads();
    buf[threadIdx.x] += t;
    __syncthreads();
  }
  if (threadIdx.x < nblk) bsum[threadIdx.x] = buf[threadIdx.x] - v;
}
__global__ __launch_bounds__(256) void scanC(int* __restrict__ out, const int* __restrict__ bsum, int m) {
  int i = blockIdx.x * 256 + threadIdx.x;
  if (i < m) out[i] += bsum[blockIdx.x];
}

// ---------------- CSR build (deterministic) ----------------
__global__ void count_kernel(const int* __restrict__ dst, int* __restrict__ cnt, int E) {
  int e = blockIdx.x * 256 + threadIdx.x;
  if (e < E) atomicAdd(&cnt[dst[e]], 1);
}
__global__ void scatter_kernel(const int* __restrict__ dst, const int* __restrict__ rowptr,
                               int* __restrict__ fill, int* __restrict__ eids, int E) {
  int e = blockIdx.x * 256 + threadIdx.x;
  if (e >= E) return;
  int d = dst[e];
  int slot = rowptr[d] + atomicAdd(&fill[d], 1);
  eids[slot] = e;
}
__global__ void bucket_sort_kernel(const int* __restrict__ rowptr, int* __restrict__ eids, int n) {
  int v = blockIdx.x * 256 + threadIdx.x;
  if (v >= n) return;
  int lo = rowptr[v], hi = rowptr[v + 1];
  for (int a = lo + 1; a < hi; ++a) {
    int key = eids[a];
    int b = a - 1;
    while (b >= lo && eids[b] > key) { eids[b + 1] = eids[b]; --b; }
    eids[b + 1] = key;
  }
}
__global__ void count2_kernel(const int* __restrict__ src, const int* __restrict__ dst,
                              const int* __restrict__ rank, int kk, int* __restrict__ cnt2, int E) {
  int e = blockIdx.x * 256 + threadIdx.x;
  if (e >= E) return;
  int rs = rank[src[e]], rd = rank[dst[e]];
  if (rs < kk && rd < kk) atomicAdd(&cnt2[rd], 1);
}
__global__ void dinv_kernel(const int* __restrict__ cnt, float* __restrict__ dinv, int n) {
  int i = blockIdx.x * 256 + threadIdx.x;
  if (i < n) dinv[i] = 1.0f / sqrtf((float)(cnt[i] + 1));
}
// padded degree (multiple of 8) from full in-degree
__global__ void pdeg_kernel(const int* __restrict__ cnt, int* __restrict__ pdeg, int n) {
  int i = blockIdx.x * 256 + threadIdx.x;
  if (i < n) pdeg[i] = ((cnt[i] + 7) >> 3) << 3;
}
// map: original CSR slot -> padded slot (preserves in-node ascending edge order)
__global__ void map_kernel(const int* __restrict__ rowptr, const int* __restrict__ prow,
                           int* __restrict__ map, int n) {
  int v = blockIdx.x * 256 + threadIdx.x;
  if (v >= n) return;
  int lo = rowptr[v], hi = rowptr[v + 1], p0 = prow[v];
  for (int j = 0; j < hi - lo; ++j) map[lo + j] = p0 + j;
}

// per-padded-slot operands: {src_row, dinv_bits}. Dead/pad slots = {0, 0.0f}
// (valid dummy row x zero weight -> adds +/-0, bitwise no-op in the chain).
__global__ void csr_prep(const int* __restrict__ eids, const int* __restrict__ src,
                         const int* __restrict__ map,
                         const int* __restrict__ rank, int kk,
                         const float* __restrict__ dinv,
                         int2* __restrict__ pk, int E) {
  int idx = blockIdx.x * 256 + threadIdx.x;
  if (idx >= E) return;
  int s = src[eids[idx]];
  int pos = map[idx];
  if (rank) {
    int r = rank[s];
    pk[pos] = (r < kk) ? make_int2(r, __float_as_int(dinv[r])) : make_int2(0, 0);
  } else {
    pk[pos] = make_int2(s, __float_as_int(dinv[s]));
  }
}

// ---------------- GEMM (OpenBLAS rounding: per-(i,j) acc, k ascending, FMA) ----
__global__ __launch_bounds__(256) void gemm_128(const float* __restrict__ X,
                                                const float* __restrict__ W,
                                                float* __restrict__ C, int n) {
  const int row0 = blockIdx.x * 64;
  const int c0 = (threadIdx.x & 15) << 3;
  const int r0 = (threadIdx.x >> 4) << 2;

  int gr[4];
  bool inb[4];
  #pragma unroll
  for (int i = 0; i < 4; ++i) { gr[i] = row0 + r0 + i; inb[i] = gr[i] < n; }

  float acc[4][8];
  #pragma unroll
  for (int i = 0; i < 4; ++i)
    #pragma unroll
    for (int j = 0; j < 8; ++j) acc[i][j] = 0.f;

  for (int kc = 0; kc < 32; ++kc) {
    float xv[4][4];
    #pragma unroll
    for (int i = 0; i < 4; ++i) {
      float4 t = inb[i] ? *(const float4*)&X[(size_t)gr[i] * DH + kc * 4]
                        : make_float4(0.f, 0.f, 0.f, 0.f);
      xv[i][0] = t.x; xv[i][1] = t.y; xv[i][2] = t.z; xv[i][3] = t.w;
    }
    #pragma unroll
    for (int kk = 0; kk < 4; ++kk) {
      const float* wrow = &W[(kc * 4 + kk) * 128 + c0];
      float4 wa = *(const float4*)(wrow);
      float4 wb = *(const float4*)(wrow + 4);
      float wv[8] = {wa.x, wa.y, wa.z, wa.w, wb.x, wb.y, wb.z, wb.w};
      #pragma unroll
      for (int i = 0; i < 4; ++i)
        #pragma unroll
        for (int j = 0; j < 8; ++j)
          acc[i][j] = fmaf(xv[i][kk], wv[j], acc[i][j]);
    }
  }
  #pragma unroll
  for (int i = 0; i < 4; ++i) {
    if (inb[i]) {
      *(float4*)&C[(size_t)gr[i] * DH + c0] =
          make_float4(acc[i][0], acc[i][1], acc[i][2], acc[i][3]);
      *(float4*)&C[(size_t)gr[i] * DH + c0 + 4] =
          make_float4(acc[i][4], acc[i][5], acc[i][6], acc[i][7]);
    }
  }
}

// ---------------- GCN conv: np.add.at order, fully unconditional 8-wide batches ----
// Padded CSR: every chunk is 8 valid slots (dummies = row0 x weight 0 -> adds +/-0,
// bitwise no-op). Loads are branch-free => compiler batches 8 pk + 8 h loads per round.
__global__ __launch_bounds__(256) void conv_kernel(
    const float* __restrict__ h, const float* __restrict__ bias,
    const int* __restrict__ prow, const int* __restrict__ pdeg,
    const int2* __restrict__ pk,
    const int* __restrict__ sel,   // level2: new->orig (null for level1)
    const float* __restrict__ dinv,
    float* __restrict__ out, int nodes) {
  #pragma clang fp contract(off)
  int node = blockIdx.x * 2 + (threadIdx.x >> 7);
  int dim = threadIdx.x & 127;
  if (node >= nodes) return;
  int v_orig = sel ? sel[node] : node;
  float dv = dinv[node];
  float acc = 0.f;
  int base = prow[v_orig];
  int chunks = pdeg[v_orig] >> 3;
  for (int cc = 0; cc < chunks; ++cc) {
    int2 p[8];
    float hv[8];
    #pragma unroll
    for (int q = 0; q < 8; ++q) p[q] = pk[base + q];
    #pragma unroll
    for (int q = 0; q < 8; ++q) hv[q] = h[(size_t)p[q].x * DH + dim];
    #pragma unroll
    for (int q = 0; q < 8; ++q) {
      float nm = __int_as_float(p[q].y) * dv;
      float t = hv[q] * nm;
      acc = acc + t;
    }
    base += 8;
  }
  float selft = h[(size_t)node * DH + dim] * (dv * dv);
  float r = (acc + selft) + bias[dim];
  out[(size_t)node * DH + dim] = r > 0.f ? r : 0.f;
}

// ---------------- score (OpenBLAS sgemv_t rounding) + fused keys/hist ----------------
__global__ __launch_bounds__(256) void score_kernel(const float* __restrict__ h,
    const float* __restrict__ attn, const float* __restrict__ nrm,
    float* __restrict__ score, unsigned* __restrict__ s32,
    int* __restrict__ hist, int n) {
  __shared__ float at[128];
  if (threadIdx.x < 32) {
    *(float4*)&at[threadIdx.x * 4] = *(const float4*)&attn[threadIdx.x * 4];
  }
  __syncthreads();
  int row = blockIdx.x * 256 + threadIdx.x;
  if (row >= n) return;
  const float* hr = &h[(size_t)row * DH];
  float c[16];
  #pragma unroll
  for (int j = 0; j < 16; ++j) c[j] = 0.f;
  #pragma unroll
  for (int t = 0; t < 8; ++t) {
    #pragma unroll
    for (int j4 = 0; j4 < 4; ++j4) {
      float4 hv = *(const float4*)&hr[t * 16 + j4 * 4];
      float4 av = *(const float4*)&at[t * 16 + j4 * 4];
      c[j4 * 4 + 0] = fmaf(hv.x, av.x, c[j4 * 4 + 0]);
      c[j4 * 4 + 1] = fmaf(hv.y, av.y, c[j4 * 4 + 1]);
      c[j4 * 4 + 2] = fmaf(hv.z, av.z, c[j4 * 4 + 2]);
      c[j4 * 4 + 3] = fmaf(hv.w, av.w, c[j4 * 4 + 3]);
    }
  }
  float s8[8];
  #pragma unroll
  for (int l = 0; l < 8; ++l) s8[l] = c[l] + c[l + 8];
  float s4[4];
  #pragma unroll
  for (int l = 0; l < 4; ++l) s4[l] = s8[l] + s8[l + 4];
  float dot = (s4[0] + s4[1]) + (s4[2] + s4[3]);
  float q = dot / nrm[0];
  float sc = (float)tanh((double)q);
  score[row] = sc;
  unsigned u = __float_as_uint(sc);
  unsigned sb = (u & 0x80000000u) ? ~u : (u | 0x80000000u);
  s32[row] = sb;
  atomicAdd(&hist[sb >> 16], 1);
}

// ---------------- bucketed exact ranking ----------------
__global__ void scatter32_kernel(const unsigned* __restrict__ s32, const int* __restrict__ start,
                                 int* __restrict__ fill2, unsigned long long* __restrict__ mem64,
                                 int n) {
  int i = blockIdx.x * 256 + threadIdx.x;
  if (i >= n) return;
  unsigned si = s32[i];
  int b = si >> 16;
  int pos = start[b] + atomicAdd(&fill2[b], 1);
  mem64[pos] = ((unsigned long long)si << 32) | (unsigned)(~i);
}
__global__ void rank_bucket_kernel(const unsigned* __restrict__ s32, const int* __restrict__ start,
                                   const int* __restrict__ hist,
                                   const unsigned long long* __restrict__ mem64,
                                   int n, int* __restrict__ rank) {
  int i = blockIdx.x * 256 + threadIdx.x;
  if (i >= n) return;
  unsigned si = s32[i];
  int b = si >> 16;
  int lo = start[b], m = hist[b];
  unsigned long long ki = ((unsigned long long)si << 32) | (unsigned)(~i);
  int cnt = n - lo - m;  // all elements in higher buckets have greater keys
  for (int t = 0; t < m; ++t) cnt += (mem64[lo + t] > ki) ? 1 : 0;
  rank[i] = cnt;
}

__global__ void select_kernel(const float* __restrict__ score, const int* __restrict__ rank,
                              int k, int* __restrict__ sel, float* __restrict__ vals, int n) {
  int i = blockIdx.x * 256 + threadIdx.x;
  if (i >= n) return;
  int r = rank[i];
  if (r < k) { sel[r] = i; vals[r] = score[i]; }
}

__global__ __launch_bounds__(256) void gather_kernel(const float* __restrict__ h,
    const int* __restrict__ sel, const float* __restrict__ vals,
    float* __restrict__ out, int k) {
  int lane = threadIdx.x & 31;
  int r = blockIdx.x * 8 + (threadIdx.x >> 5);
  if (r >= k) return;
  float v = vals[r];
  int s = sel[r];
  float4 x = *(const float4*)&h[(size_t)s * DH + (lane << 2)];
  *(float4*)&out[(size_t)r * DH + (lane << 2)] =
      make_float4(x.x * v, x.y * v, x.z * v, x.w * v);
}

// ---------------- host ----------------
extern "C" void kernel_launch(void* const* d_in, const int* in_sizes, int n_in,
                              void* d_out, int out_size, void* d_ws, size_t ws_size,
                              hipStream_t stream) {
  const float* X  = (const float*)d_in[0];
  const int*   ei = (const int*)d_in[1];
  const float* W1 = (const float*)d_in[3];
  const float* b1 = (const float*)d_in[4];
  const float* a1 = (const float*)d_in[5];
  const float* W2 = (const float*)d_in[6];
  const float* b2 = (const float*)d_in[7];
  const float* a2 = (const float*)d_in[8];
  float* out = (float*)d_out;

  const int n  = in_sizes[0] / DH;
  const int E  = in_sizes[1] / 2;
  const int k1 = (4 * n + 4) / 5;
  const int k2 = (4 * k1 + 4) / 5;
  const int Pmax = E + 8 * n;   // upper bound on padded slot count
  const int* src = ei;
  const int* dst = ei + E;

  char* w = (char*)d_ws;
  size_t off = 0;
  auto alloc = [&](size_t bytes) { void* p = w + off; off += (bytes + 255) & ~(size_t)255; return p; };
  float* hA     = (float*)alloc((size_t)n * DH * 4);
  float* hB     = (float*)alloc((size_t)n * DH * 4);
  float* xp     = (float*)alloc((size_t)k1 * DH * 4);
  int*   cnt    = (int*)  alloc((size_t)n * 4);
  int*   rowptr = (int*)  alloc((size_t)(n + 1) * 4);
  int*   fill   = (int*)  alloc((size_t)n * 4);
  int*   eids   = (int*)  alloc((size_t)E * 4);
  int*   pdeg   = (int*)  alloc((size_t)n * 4);
  int*   prow   = (int*)  alloc((size_t)n * 4);
  int*   map    = (int*)  alloc((size_t)E * 4);
  int2*  pk     = (int2*) alloc((size_t)Pmax * 8);
  int*   cnt2   = (int*)  alloc((size_t)k1 * 4);
  float* dinv1  = (float*)alloc((size_t)n * 4);
  float* dinv2  = (float*)alloc((size_t)k1 * 4);
  float* score1 = (float*)alloc((size_t)n * 4);
  float* score2 = (float*)alloc((size_t)k1 * 4);
  int*   rank1  = (int*)  alloc((size_t)n * 4);
  int*   rank2  = (int*)  alloc((size_t)k1 * 4);
  unsigned* s32 = (unsigned*)alloc((size_t)n * 4);
  int*   hist   = (int*)  alloc((size_t)NB * 4);
  int*   start  = (int*)  alloc((size_t)NB * 4);
  int*   fill2  = (int*)  alloc((size_t)NB * 4);
  unsigned long long* mem64 = (unsigned long long*)alloc((size_t)n * 8);
  int*   bsum   = (int*)  alloc((size_t)1024 * 4);
  int*   sel1   = (int*)  alloc((size_t)k1 * 4);
  float* vals1  = (float*)alloc((size_t)k1 * 4);
  int*   sel2   = (int*)  alloc((size_t)k2 * 4);
  float* vals2  = (float*)alloc((size_t)k2 * 4);
  float* nrm1   = (float*)alloc(256);
  float* nrm2   = (float*)alloc(256);

  auto scan3 = [&](const int* in, int* outp, int m) {
    int nblk = CDIV(m, 256);
    scanA<<<nblk, 256, 0, stream>>>(in, outp, bsum, m);
    scanB<<<1, 1024, 0, stream>>>(bsum, nblk);
    scanC<<<nblk, 256, 0, stream>>>(outp, bsum, m);
  };
  auto rank_pass = [&](const unsigned* s32p, int* rank, int nL) {
    scan3(hist, start, NB);
    scatter32_kernel<<<CDIV(nL, 256), 256, 0, stream>>>(s32p, start, fill2, mem64, nL);
    rank_bucket_kernel<<<CDIV(nL, 256), 256, 0, stream>>>(s32p, start, hist, mem64, nL, rank);
  };

  // ---- CSR build ----
  fill_two_i32<<<CDIV(n, 256), 256, 0, stream>>>(cnt, fill, n);
  count_kernel<<<CDIV(E, 256), 256, 0, stream>>>(dst, cnt, E);
  scan3(cnt, rowptr, n);
  set_one_i32<<<1, 64, 0, stream>>>(rowptr + n, E);
  scatter_kernel<<<CDIV(E, 256), 256, 0, stream>>>(dst, rowptr, fill, eids, E);
  bucket_sort_kernel<<<CDIV(n, 256), 256, 0, stream>>>(rowptr, eids, n);
  pdeg_kernel<<<CDIV(n, 256), 256, 0, stream>>>(cnt, pdeg, n);
  scan3(pdeg, prow, n);
  map_kernel<<<CDIV(n, 256), 256, 0, stream>>>(rowptr, prow, map, n);
  fill_pk<<<CDIV(Pmax, 256), 256, 0, stream>>>(pk, Pmax);

  // ---- level 1 ----
  norm_kernel<<<1, 64, 0, stream>>>(a1, nrm1);
  gemm_128<<<CDIV(n, 64), 256, 0, stream>>>(X, W1, hA, n);
  dinv_kernel<<<CDIV(n, 256), 256, 0, stream>>>(cnt, dinv1, n);
  csr_prep<<<CDIV(E, 256), 256, 0, stream>>>(eids, src, map, nullptr, 0, dinv1, pk, E);
  conv_kernel<<<CDIV(n, 2), 256, 0, stream>>>(hA, b1, prow, pdeg, pk, nullptr, dinv1, hB, n);
  fill_hist<<<NB / 256, 256, 0, stream>>>(hist, fill2);
  score_kernel<<<CDIV(n, 256), 256, 0, stream>>>(hB, a1, nrm1, score1, s32, hist, n);
  rank_pass(s32, rank1, n);
  select_kernel<<<CDIV(n, 256), 256, 0, stream>>>(score1, rank1, k1, sel1, vals1, n);
  gather_kernel<<<CDIV(k1, 8), 256, 0, stream>>>(hB, sel1, vals1, xp, k1);

  // ---- level 2 ----
  norm_kernel<<<1, 64, 0, stream>>>(a2, nrm2);
  gemm_128<<<CDIV(k1, 64), 256, 0, stream>>>(xp, W2, hA, k1);
  fill_i32<<<CDIV(k1, 256), 256, 0, stream>>>(cnt2, 0, k1);
  count2_kernel<<<CDIV(E, 256), 256, 0, stream>>>(src, dst, rank1, k1, cnt2, E);
  dinv_kernel<<<CDIV(k1, 256), 256, 0, stream>>>(cnt2, dinv2, k1);
  csr_prep<<<CDIV(E, 256), 256, 0, stream>>>(eids, src, map, rank1, k1, dinv2, pk, E);
  conv_kernel<<<CDIV(k1, 2), 256, 0, stream>>>(hA, b2, prow, pdeg, pk, sel1, dinv2, hB, k1);
  fill_hist<<<NB / 256, 256, 0, stream>>>(hist, fill2);
  score_kernel<<<CDIV(k1, 256), 256, 0, stream>>>(hB, a2, nrm2, score2, s32, hist, k1);
  rank_pass(s32, rank2, k1);
  select_kernel<<<CDIV(k1, 256), 256, 0, stream>>>(score2, rank2, k2, sel2, vals2, k1);
  gather_kernel<<<CDIV(k2, 8), 256, 0, stream>>>(hB, sel2, vals2, out, k2);
}